// Round 3
// baseline (380.420 us; speedup 1.0000x reference)
//
#include <hip/hip_runtime.h>
#include <math.h>

#define S_TOK 8192
#define M_DIM 4096
#define NEXP 64
#define CAPACITY 256   // K * ceil(S/E) = 2*128
#define NCHUNK 128     // S / 64
#define KS 8           // split-K slices
#define KSL 512        // slice length (KS*KSL = M_DIM)
#define BKL 32         // k per LDS chunk
#define NCL (KSL / BKL)

// ---------------------------------------------------------------------------
// K1: partial logits, split-K. Wave-uniform experts: wave w owns experts
// 16w..16w+15 (scalar s_load path for wg), lane = token (LDS only for x,
// XOR-swizzled transpose, conflict-free). Grid 128 tiles x 8 slices.
// ---------------------------------------------------------------------------
__global__ __launch_bounds__(256) void k_logits(
    const float* __restrict__ x, const float* __restrict__ wg,
    float* __restrict__ part)
{
    __shared__ float xt[2][BKL * 64];   // [k][tok ^ k], 8KB per buffer
    const int tid = threadIdx.x;
    const int tile = blockIdx.x >> 3;
    const int ks = blockIdx.x & 7;
    const int t0 = tile * 64;
    const int kb = ks * KSL;
    const int wave = __builtin_amdgcn_readfirstlane(tid >> 6);  // uniform
    const int lane = tid & 63;
    const int e0 = wave * 16;

    float4 rx[2];
    auto ld = [&](int kc) {
        #pragma unroll
        for (int i = 0; i < 2; ++i) {
            const int item = tid + 256 * i;
            const int tok = item >> 3, kq = item & 7;
            rx[i] = *(const float4*)(x + (size_t)(t0 + tok) * M_DIM + kc + 4 * kq);
        }
    };
    auto st = [&](int buf) {
        #pragma unroll
        for (int i = 0; i < 2; ++i) {
            const int item = tid + 256 * i;
            const int tok = item >> 3, kq = item & 7;
            const float v[4] = {rx[i].x, rx[i].y, rx[i].z, rx[i].w};
            #pragma unroll
            for (int j = 0; j < 4; ++j) {
                const int k = 4 * kq + j;
                xt[buf][k * 64 + (tok ^ k)] = v[j];   // 2-way max on stores
            }
        }
    };

    float acc[16] = {};
    ld(kb);
    st(0);
    __syncthreads();
    for (int c = 0; c < NCL; ++c) {
        const int buf = c & 1;
        if (c + 1 < NCL) ld(kb + (c + 1) * BKL);
        const float* wrow = wg + (size_t)e0 * M_DIM + kb + c * BKL;
        #pragma unroll
        for (int k4 = 0; k4 < BKL; k4 += 4) {
            float4 wv[16];                 // wave-uniform -> SGPRs via s_load
            #pragma unroll
            for (int e = 0; e < 16; ++e)
                wv[e] = *(const float4*)(wrow + (size_t)e * M_DIM + k4);
            float a[4];
            #pragma unroll
            for (int j = 0; j < 4; ++j) {
                const int k = k4 + j;
                a[j] = xt[buf][k * 64 + (lane ^ k)];
            }
            #pragma unroll
            for (int e = 0; e < 16; ++e) {
                acc[e] = fmaf(a[0], wv[e].x, acc[e]);
                acc[e] = fmaf(a[1], wv[e].y, acc[e]);
                acc[e] = fmaf(a[2], wv[e].z, acc[e]);
                acc[e] = fmaf(a[3], wv[e].w, acc[e]);
            }
        }
        __syncthreads();
        if (c + 1 < NCL) st(buf ^ 1);
        __syncthreads();
    }
    float* po = part + ((size_t)ks * S_TOK + t0 + lane) * NEXP + e0;
    #pragma unroll
    for (int j = 0; j < 4; ++j) {
        float4 v;
        v.x = acc[4*j]; v.y = acc[4*j+1]; v.z = acc[4*j+2]; v.w = acc[4*j+3];
        *(float4*)(po + 4 * j) = v;
    }
}

// ---------------------------------------------------------------------------
// K2: fused reduce (softmax+top2+me) + in-chunk rank/histogram.
// Block = 64-token chunk; 4 waves x 16 tokens (lane=expert); wave0 ballots.
// ---------------------------------------------------------------------------
__global__ __launch_bounds__(256) void k_route(
    const float* __restrict__ part, float* __restrict__ me_g,
    int* __restrict__ pack_g, float* __restrict__ g0_g, float* __restrict__ g1_g,
    int* __restrict__ cnt_g /* [2][NCHUNK][64] */)
{
    __shared__ float me_sh[NEXP];
    __shared__ int   idxs[64];
    __shared__ float g0s[64], g1s[64];
    const int tid = threadIdx.x;
    const int wv = tid >> 6, lane = tid & 63;
    const int chunk = blockIdx.x;
    if (tid < NEXP) me_sh[tid] = 0.f;
    __syncthreads();

    float me_acc = 0.f;
    for (int i = 0; i < 16; ++i) {
        const int tl = wv * 16 + i;
        const int t = chunk * 64 + tl;
        float lg = 0.f;
        #pragma unroll
        for (int s = 0; s < KS; ++s)
            lg += part[((size_t)s * S_TOK + t) * NEXP + lane];

        // argmax (lowest index on tie, matching lax.top_k)
        float v = lg; int id = lane;
        #pragma unroll
        for (int off = 32; off > 0; off >>= 1) {
            float v2 = __shfl_xor(v, off);
            int   i2 = __shfl_xor(id, off);
            if (v2 > v || (v2 == v && i2 < id)) { v = v2; id = i2; }
        }
        const float mx = v; const int i0 = id;

        const float p = expf(lg - mx);
        float sum = p;
        #pragma unroll
        for (int off = 32; off > 0; off >>= 1) sum += __shfl_xor(sum, off);
        me_acc += p / sum;

        // second argmax, excluding i0
        float v1 = (lane == i0) ? -INFINITY : lg; int id1 = lane;
        #pragma unroll
        for (int off = 32; off > 0; off >>= 1) {
            float v2 = __shfl_xor(v1, off);
            int   i2 = __shfl_xor(id1, off);
            if (v2 > v1 || (v2 == v1 && i2 < id1)) { v1 = v2; id1 = i2; }
        }

        const float g0 = 1.0f / sum;
        const float g1 = expf(v1 - mx) / sum;
        const float den = fmaxf(g0 + g1, 1.1920929e-07f);
        if (lane == 0) {
            idxs[tl] = i0 | (id1 << 8);
            g0s[tl] = g0 / den;
            g1s[tl] = g1 / den;
        }
    }
    atomicAdd(&me_sh[lane], me_acc);
    __syncthreads();
    if (tid < NEXP) atomicAdd(&me_g[tid], me_sh[tid]);

    if (wv == 0) {
        const int pk = idxs[lane];
        const int e0 = pk & 255, e1 = pk >> 8;
        const unsigned long long lt = (1ull << lane) - 1ull;
        int r0 = 0, r1 = 0, c0 = 0, c1 = 0;
        #pragma unroll
        for (int e = 0; e < 64; ++e) {
            unsigned long long m0 = __ballot(e0 == e);
            unsigned long long m1 = __ballot(e1 == e);
            if (e0 == e) r0 = __popcll(m0 & lt);
            if (e1 == e) r1 = __popcll(m1 & lt);
            if (lane == e) { c0 = __popcll(m0); c1 = __popcll(m1); }
        }
        const int s = chunk * 64 + lane;
        pack_g[s] = e0 | (e1 << 8) | (r0 << 16) | (r1 << 24);
        g0_g[s] = g0s[lane];
        g1_g[s] = g1s[lane];
        cnt_g[chunk * 64 + lane] = c0;
        cnt_g[(NCHUNK + chunk) * 64 + lane] = c1;
    }
}

// ---------------------------------------------------------------------------
// K3: single-block finish — two-level scan of cnt (bases stay in LDS as u16),
// load-balance loss, and per-token combine weight.
// ---------------------------------------------------------------------------
__global__ __launch_bounds__(1024) void k_finish(
    const int* __restrict__ cnt_g, const int* __restrict__ pack_g,
    const float* __restrict__ g0_g, const float* __restrict__ g1_g,
    const float* __restrict__ me_g, float* __restrict__ wtok,
    float* __restrict__ loss)
{
    __shared__ unsigned short base16[2][NCHUNK][NEXP];  // 32KB
    __shared__ int ssum[8][128];
    __shared__ int tot0s[NEXP];
    __shared__ float lred[NEXP];
    const int tid = threadIdx.x;
    const int pair = tid & 127, seg = tid >> 7;   // pair = (k,e), 8 segs x 16 chunks
    const int k = pair >> 6, e = pair & 63;

    int cv[16], s = 0;
    #pragma unroll
    for (int c = 0; c < 16; ++c) {
        cv[c] = cnt_g[(k * NCHUNK + seg * 16 + c) * 64 + e];
        s += cv[c];
    }
    ssum[seg][pair] = s;
    __syncthreads();

    int segbase = 0, total = 0;
    #pragma unroll
    for (int s2 = 0; s2 < 8; ++s2) {
        const int v = ssum[s2][pair];
        if (s2 < seg) segbase += v;
        total += v;
    }
    if (k == 0 && seg == 0) tot0s[e] = total;
    int run = segbase;
    #pragma unroll
    for (int c = 0; c < 16; ++c) {
        base16[k][seg * 16 + c][e] = (unsigned short)run;  // run <= 8192
        run += cv[c];
    }
    __syncthreads();

    if (tid < NEXP) lred[tid] = me_g[tid] * (float)tot0s[tid];
    __syncthreads();
    if (tid == 0) {
        float t = 0.f;
        for (int i = 0; i < NEXP; ++i) t += lred[i];
        *loss = t * 9.5367431640625e-07f;  // E / S^2
    }

    #pragma unroll
    for (int j = 0; j < 8; ++j) {
        const int t = j * 1024 + tid;
        const int pk = pack_g[t];
        const int e0 = pk & 63, e1 = (pk >> 8) & 63;
        const int r0 = (pk >> 16) & 255, r1 = (pk >> 24) & 255;
        const int ch = t >> 6;
        float w = 0.f;
        if ((int)base16[0][ch][e0] + r0 < CAPACITY) w += g0_g[t];
        if ((int)base16[1][ch][e1] + tot0s[e1] + r1 < CAPACITY) w += g1_g[t];
        wtok[t] = w;
    }
}

// ---------------------------------------------------------------------------
// K4: out[s,:] = w[s] * x[s,:]   (w wave-uniform -> scalar load)
// ---------------------------------------------------------------------------
__global__ __launch_bounds__(256) void k_out(
    const float* __restrict__ x, const float* __restrict__ w_g,
    float* __restrict__ out)
{
    const int s = blockIdx.x;
    const float w = w_g[s];
    const float4* xr = (const float4*)(x + (size_t)s * M_DIM);
    float4* o = (float4*)(out + (size_t)s * M_DIM);
    #pragma unroll
    for (int i = 0; i < 4; ++i) {
        float4 v = xr[threadIdx.x + 256 * i];
        v.x *= w; v.y *= w; v.z *= w; v.w *= w;
        o[threadIdx.x + 256 * i] = v;
    }
}

// ---------------------------------------------------------------------------
extern "C" void kernel_launch(void* const* d_in, const int* in_sizes, int n_in,
                              void* d_out, int out_size, void* d_ws, size_t ws_size,
                              hipStream_t stream)
{
    const float* x  = (const float*)d_in[0];
    const float* wg = (const float*)d_in[1];
    float* out = (float*)d_out;
    float* loss = out + (size_t)S_TOK * M_DIM;

    float* part = (float*)d_ws;                         // [KS][S][E] = 16.78 MB
    float* me   = part + (size_t)KS * S_TOK * NEXP;     // [64]
    int*  pack  = (int*)(me + NEXP);                    // [S]
    float* g0   = (float*)(pack + S_TOK);               // [S]
    float* g1   = g0 + S_TOK;                           // [S]
    int*  cnt   = (int*)(g1 + S_TOK);                   // [2][128][64]
    float* wtok = (float*)(cnt + 2 * NCHUNK * 64);      // [S]

    hipMemsetAsync(me, 0, NEXP * sizeof(float), stream);

    k_logits<<<128 * KS, 256, 0, stream>>>(x, wg, part);
    k_route<<<NCHUNK, 256, 0, stream>>>(part, me, pack, g0, g1, cnt);
    k_finish<<<1, 1024, 0, stream>>>(cnt, pack, g0, g1, me, wtok, loss);
    k_out<<<S_TOK, 256, 0, stream>>>(x, wtok, out);
}